// Round 2
// baseline (1493.593 us; speedup 1.0000x reference)
//
#include <hip/hip_runtime.h>

#define NPTS   300000
#define NPAIRS 100000
#define KOFF   27
#define CIN    32
#define COUT   64
#define NGROUP 8
#define EPSV   1e-5f
#define SLOPE  0.01f

#define NTOT   (KOFF * NPAIRS)                 // 2.7M pairs
#define BINSZ  256                             // out-rows per bin (64KB LDS tile)
#define NBIN   ((NPTS + BINSZ - 1) / BINSZ)    // 1172
#define NSEG   (KOFF * NBIN)                   // 31644 segments (k, bin)
#define CONV_THREADS 576                       // 9 waves; wave w owns k = 3w..3w+2

// workspace layout (in ints): stats[16] | segCount[NSEG] | segStart[NSEG] | segCursor[NSEG] | sorted[NTOT]
#define WS_INTS_NEEDED (16 + 3 * NSEG + NTOT)

// ---------------------------------------------------------------- zero metadata (new path)
__global__ __launch_bounds__(256) void zero_meta_kernel(int* __restrict__ segCount,
                                                        float* __restrict__ stats) {
    int i = blockIdx.x * 256 + threadIdx.x;
    if (i < NSEG) segCount[i] = 0;
    if (i < 16) stats[i] = 0.f;
}

// ---------------------------------------------------------------- histogram over (k, bin) keys
__global__ __launch_bounds__(256) void hist_kernel(const int* __restrict__ out_idx,
                                                   int* __restrict__ segCount) {
    int g = blockIdx.x * 256 + threadIdx.x;
    if (g >= NTOT) return;
    int rout = out_idx[g];
    int key = (g / NPAIRS) * NBIN + (rout >> 8);
    atomicAdd(&segCount[key], 1);
}

// ---------------------------------------------------------------- exclusive scan of 31644 counts (1 block)
__global__ __launch_bounds__(1024) void scan_kernel(const int* __restrict__ cnt,
                                                    int* __restrict__ start,
                                                    int* __restrict__ cursor) {
    __shared__ int part[1024];
    const int t = threadIdx.x;
    const int per = (NSEG + 1023) / 1024;      // 31
    int lo = t * per;
    int hi = lo + per; if (hi > NSEG) hi = NSEG;
    int s = 0;
    for (int i = lo; i < hi && i >= 0; ++i) s += cnt[i];
    part[t] = s;
    __syncthreads();
    for (int off = 1; off < 1024; off <<= 1) {
        int v = (t >= off) ? part[t - off] : 0;
        __syncthreads();
        part[t] += v;
        __syncthreads();
    }
    int run = (t == 0) ? 0 : part[t - 1];      // exclusive prefix of this thread's chunk
    for (int i = lo; i < hi && i >= 0; ++i) {
        start[i] = run; cursor[i] = run;
        run += cnt[i];
    }
}

// ---------------------------------------------------------------- scatter pairs into segment lists
// entry = (rlocal[8b] << 19) | rin[19b]; k implicit in segment id
__global__ __launch_bounds__(256) void scatter_kernel(const int* __restrict__ out_idx,
                                                      const int* __restrict__ in_idx,
                                                      int* __restrict__ segCursor,
                                                      int* __restrict__ sorted) {
    int g = blockIdx.x * 256 + threadIdx.x;
    if (g >= NTOT) return;
    int rout = out_idx[g];
    int rin  = in_idx[g];
    int key = (g / NPAIRS) * NBIN + (rout >> 8);
    int pos = atomicAdd(&segCursor[key], 1);
    sorted[pos] = ((rout & (BINSZ - 1)) << 19) | rin;
}

// ---------------------------------------------------------------- binned conv: LDS accumulate, no global atomics
// One block per 256-row out bin. 9 waves; wave w processes k = 3w..3w+2 with W[k][:,lane]
// in 32 VGPRs. Pair rows gathered via wave-uniform (scalar) loads, depth-2 pipelined.
// Accumulation via ds_add_f32 (lgkmcnt — does NOT enter the vmcnt wait chain).
// Bin flushed once as a coalesced streaming store: zero_kernel eliminated.
__global__ __launch_bounds__(CONV_THREADS) void conv_binned_kernel(
    const float* __restrict__ feats, const float* __restrict__ weight,
    const int* __restrict__ sorted, const int* __restrict__ segStart,
    const int* __restrict__ segCount, float* __restrict__ out)
{
    __shared__ float accS[BINSZ * COUT];       // 64KB
    const int bin  = blockIdx.x;
    const int lane = threadIdx.x & 63;
    const int wv   = threadIdx.x >> 6;         // 0..8

    for (int i = threadIdx.x; i < BINSZ * COUT; i += CONV_THREADS) accS[i] = 0.f;
    __syncthreads();

#pragma unroll
    for (int kk = 0; kk < 3; ++kk) {
        const int k = wv * 3 + kk;             // 9 waves x 3 = 27, exact
        const int s = k * NBIN + bin;
        const int st  = segStart[s];
        const int len = segCount[s];
        if (len <= 0) continue;

        float w[CIN];
        const float* wk = weight + k * (CIN * COUT) + lane;
#pragma unroll
        for (int i = 0; i < CIN; ++i) w[i] = wk[i * COUT];

        auto loadrow = [&](int idx, float* R) -> int {
            int e = __builtin_amdgcn_readfirstlane(sorted[idx]);
            const float* f = feats + (size_t)(e & 0x7FFFF) * CIN;
#pragma unroll
            for (int i = 0; i < CIN; ++i) R[i] = f[i];
            return e >> 19;
        };
        auto compute = [&](const float* R, int rl) {
            float a0 = 0.f, a1 = 0.f;
#pragma unroll
            for (int i = 0; i < CIN; i += 2) {
                a0 = fmaf(R[i],     w[i],     a0);
                a1 = fmaf(R[i + 1], w[i + 1], a1);
            }
            atomicAdd(&accS[rl * COUT + lane], a0 + a1);
        };

        const int pend = st + len;
        float A[CIN], B[CIN];
        int rlA = loadrow(st, A);
        if (len == 1) { compute(A, rlA); continue; }
        int rlB = loadrow(st + 1, B);
        int j = st;                            // A = entry j, B = entry j+1
        while (true) {
            compute(A, rlA);
            if (j + 2 < pend) rlA = loadrow(j + 2, A);
            else { compute(B, rlB); break; }
            compute(B, rlB);
            if (j + 3 < pend) rlB = loadrow(j + 3, B);
            else { compute(A, rlA); break; }
            j += 2;
        }
    }
    __syncthreads();

    // flush: wave per row, 64-lane coalesced 256B stores
    const int base = bin << 8;
    for (int r = wv; r < BINSZ; r += 9) {
        int row = base + r;
        if (row < NPTS) out[(size_t)row * COUT + lane] = accS[r * COUT + lane];
    }
}

// ---------------------------------------------------------------- fallback path (ws too small): proven atomic conv
#define PAIRS_PER_BLOCK 256
#define BLOCKS_PER_K ((NPAIRS + PAIRS_PER_BLOCK - 1) / PAIRS_PER_BLOCK)  // 391

__global__ __launch_bounds__(256) void zero_kernel(float4* __restrict__ out4, int n4,
                                                   float* __restrict__ stats) {
    int i = blockIdx.x * blockDim.x + threadIdx.x;
    if (i < n4) out4[i] = make_float4(0.f, 0.f, 0.f, 0.f);
    if (blockIdx.x == 0 && threadIdx.x < 16) stats[threadIdx.x] = 0.f;
}

__global__ __launch_bounds__(256) void conv_kernel(
    const float* __restrict__ feats, const float* __restrict__ weight,
    const int* __restrict__ in_idx, const int* __restrict__ out_idx,
    float* __restrict__ out)
{
    const int lane = threadIdx.x & 63;
    const int wave = threadIdx.x >> 6;
    const int k     = blockIdx.x / BLOCKS_PER_K;
    const int pair0 = (blockIdx.x % BLOCKS_PER_K) * PAIRS_PER_BLOCK;

    float w[CIN];
    const float* wk = weight + k * (CIN * COUT) + lane;
#pragma unroll
    for (int i = 0; i < CIN; ++i) w[i] = wk[i * COUT];

    const int per_wave = PAIRS_PER_BLOCK / 4;
    int p    = pair0 + wave * per_wave;
    int pend = p + per_wave;
    if (pend > NPAIRS) pend = NPAIRS;

    const int* ii = in_idx  + k * NPAIRS;
    const int* oi = out_idx + k * NPAIRS;

    for (; p < pend; ++p) {
        int rin  = __builtin_amdgcn_readfirstlane(ii[p]);
        int rout = __builtin_amdgcn_readfirstlane(oi[p]);
        const float* frow = feats + (size_t)rin * CIN;
        float acc = 0.f;
#pragma unroll
        for (int i = 0; i < CIN; ++i)
            acc = fmaf(frow[i], w[i], acc);
        atomicAdd(out + (size_t)rout * COUT + lane, acc);
    }
}

// ---------------------------------------------------------------- group stats (sum, sumsq)
__global__ __launch_bounds__(256) void stats_kernel(const float4* __restrict__ out4,
                                                    float* __restrict__ stats) {
    const int tid  = blockIdx.x * 256 + threadIdx.x;
    const int ntid = gridDim.x * 256;                 // multiple of 16
    const int n4   = NPTS * COUT / 4;

    float s = 0.f, ss = 0.f;
    for (int i = tid; i < n4; i += ntid) {
        float4 v = out4[i];
        s  += v.x + v.y + v.z + v.w;
        ss += v.x * v.x + v.y * v.y + v.z * v.z + v.w * v.w;
    }
    s  += __shfl_xor(s,  1, 64);  ss += __shfl_xor(ss,  1, 64);
    s  += __shfl_xor(s, 16, 64);  ss += __shfl_xor(ss, 16, 64);
    s  += __shfl_xor(s, 32, 64);  ss += __shfl_xor(ss, 32, 64);

    __shared__ float sm_s[4][NGROUP];
    __shared__ float sm_ss[4][NGROUP];
    const int lane = threadIdx.x & 63;
    const int wv   = threadIdx.x >> 6;
    if (lane < 16 && (lane & 1) == 0) {
        sm_s [wv][lane >> 1] = s;
        sm_ss[wv][lane >> 1] = ss;
    }
    __syncthreads();
    if (threadIdx.x < NGROUP) {
        float ts = 0.f, tss = 0.f;
#pragma unroll
        for (int wvi = 0; wvi < 4; ++wvi) { ts += sm_s[wvi][threadIdx.x]; tss += sm_ss[wvi][threadIdx.x]; }
        atomicAdd(stats + threadIdx.x,          ts);
        atomicAdd(stats + NGROUP + threadIdx.x, tss);
    }
}

// ---------------------------------------------------------------- normalize + affine + leaky relu
__global__ __launch_bounds__(256) void norm_kernel(float4* __restrict__ out4, int n4,
                                                   const float* __restrict__ stats,
                                                   const float* __restrict__ gamma,
                                                   const float* __restrict__ beta) {
    int i = blockIdx.x * blockDim.x + threadIdx.x;
    if (i >= n4) return;
    int c0 = (i & 15) * 4;
    int g  = c0 >> 3;
    const float cnt = (float)NPTS * (COUT / NGROUP);
    float mean = stats[g] / cnt;
    float var  = stats[8 + g] / cnt - mean * mean;
    float inv  = rsqrtf(var + EPSV);
    float4 v  = out4[i];
    float4 ga = *(const float4*)(gamma + c0);
    float4 be = *(const float4*)(beta  + c0);
    float x;
    x = (v.x - mean) * inv * ga.x + be.x; v.x = x >= 0.f ? x : SLOPE * x;
    x = (v.y - mean) * inv * ga.y + be.y; v.y = x >= 0.f ? x : SLOPE * x;
    x = (v.z - mean) * inv * ga.z + be.z; v.z = x >= 0.f ? x : SLOPE * x;
    x = (v.w - mean) * inv * ga.w + be.w; v.w = x >= 0.f ? x : SLOPE * x;
    out4[i] = v;
}

// ---------------------------------------------------------------- launch
extern "C" void kernel_launch(void* const* d_in, const int* in_sizes, int n_in,
                              void* d_out, int out_size, void* d_ws, size_t ws_size,
                              hipStream_t stream) {
    const float* feats  = (const float*)d_in[0];
    const float* weight = (const float*)d_in[1];
    const float* gamma  = (const float*)d_in[2];
    const float* beta   = (const float*)d_in[3];
    const int*   in_idx = (const int*)d_in[4];
    const int*   out_idx= (const int*)d_in[5];
    float* out   = (float*)d_out;

    int n4 = out_size / 4;                 // 4.8M float4
    int zb = (n4 + 255) / 256;

    if (ws_size >= (size_t)WS_INTS_NEEDED * 4) {
        // ---- binned, atomic-free conv path ----
        float* stats    = (float*)d_ws;
        int* segCount   = (int*)d_ws + 16;
        int* segStart   = segCount + NSEG;
        int* segCursor  = segStart + NSEG;
        int* sorted     = segCursor + NSEG;

        int pb = (NTOT + 255) / 256;       // 10547
        zero_meta_kernel<<<(NSEG + 255) / 256, 256, 0, stream>>>(segCount, stats);
        hist_kernel<<<pb, 256, 0, stream>>>(out_idx, segCount);
        scan_kernel<<<1, 1024, 0, stream>>>(segCount, segStart, segCursor);
        scatter_kernel<<<pb, 256, 0, stream>>>(out_idx, in_idx, segCursor, sorted);
        conv_binned_kernel<<<NBIN, CONV_THREADS, 0, stream>>>(feats, weight, sorted,
                                                              segStart, segCount, out);
        stats_kernel<<<2048, 256, 0, stream>>>((const float4*)out, stats);
        norm_kernel<<<zb, 256, 0, stream>>>((float4*)out, n4, stats, gamma, beta);
    } else {
        // ---- fallback: proven atomic path ----
        float* stats = (float*)d_ws;
        zero_kernel<<<zb, 256, 0, stream>>>((float4*)out, n4, stats);
        conv_kernel<<<KOFF * BLOCKS_PER_K, 256, 0, stream>>>(feats, weight, in_idx, out_idx, out);
        stats_kernel<<<2048, 256, 0, stream>>>((const float4*)out, stats);
        norm_kernel<<<zb, 256, 0, stream>>>((float4*)out, n4, stats, gamma, beta);
    }
}